// Round 7
// baseline (315.294 us; speedup 1.0000x reference)
//
#include <hip/hip_runtime.h>
#include <hip/hip_bf16.h>

typedef short s8v  __attribute__((ext_vector_type(8)));
typedef float f16v __attribute__((ext_vector_type(16)));

__device__ __forceinline__ unsigned short f2bf(float x) {   // RTN-even
    unsigned u = __float_as_uint(x);
    unsigned r = ((u >> 16) & 1u) + 0x7FFFu;
    return (unsigned short)((u + r) >> 16);
}
__device__ __forceinline__ float bf2f(unsigned short h) {
    return __uint_as_float(((unsigned)h) << 16);
}

// ---------------- hist only (critical chain head, keep it tiny) ----------------
__global__ __launch_bounds__(256) void hist_kernel(
    const int* __restrict__ edge_index, int* __restrict__ deg, int E)
{
    int e = blockIdx.x * 256 + threadIdx.x;
    if (e < E) atomicAdd(&deg[edge_index[E + e]], 1);
}

// ---------------- CSR scan ----------------
__global__ __launch_bounds__(1024) void scanA_kernel(
    const int* __restrict__ deg, int* __restrict__ row_start,
    int* __restrict__ btot, int N)
{
    __shared__ int wtot[16];
    __shared__ int woff[16];
    const int tid = threadIdx.x, lane = tid & 63, wid = tid >> 6;
    int i = blockIdx.x * 1024 + tid;
    int v = (i < N) ? deg[i] : 0;
    int x = v;
    #pragma unroll
    for (int d = 1; d < 64; d <<= 1) {
        int t = __shfl_up(x, d, 64);
        if (lane >= d) x += t;
    }
    if (lane == 63) wtot[wid] = x;
    __syncthreads();
    if (wid == 0 && lane < 16) {
        int s = wtot[lane];
        int y = s;
        #pragma unroll
        for (int d = 1; d < 16; d <<= 1) {
            int t = __shfl_up(y, d, 16);
            if (lane >= d) y += t;
        }
        woff[lane] = y - s;
        if (lane == 15) btot[blockIdx.x] = y;
    }
    __syncthreads();
    if (i < N) row_start[i] = woff[wid] + (x - v);
}

// scanC with scanB inlined: every block redundantly wave-scans the <=64
// block totals (cheap), then applies its own exclusive offset.
__global__ __launch_bounds__(1024) void scanC_kernel(
    int* __restrict__ row_start, int* __restrict__ cursor,
    const int* __restrict__ btot, int nB, int N)
{
    __shared__ int incl[64];
    const int tid = threadIdx.x;
    if (tid < 64) {
        int v = (tid < nB) ? btot[tid] : 0;
        int x = v;
        #pragma unroll
        for (int d = 1; d < 64; d <<= 1) {
            int t = __shfl_up(x, d, 64);
            if (tid >= d) x += t;
        }
        incl[tid] = x;
    }
    __syncthreads();
    int off = (blockIdx.x == 0) ? 0 : incl[blockIdx.x - 1];
    int i = blockIdx.x * 1024 + tid;
    if (i < N) {
        int r = row_start[i] + off;
        row_start[i] = r;
        cursor[i]    = r;
    }
    if (blockIdx.x == (unsigned)(nB - 1) && tid == 0)
        row_start[N] = incl[nB - 1];
}

// ---------------- mega: relctx | fill(records) | bprep ----------------
// fill writes ONE aligned 16B record per edge {src, entity[src], et, norm}
// instead of 36B across three arrays -> kills partial-line write amplification.
// X0 materialization is gone: layer1 reads ent_tab f32 directly.
__global__ __launch_bounds__(256) void mega_kernel(
    // relctx
    const float* __restrict__ DAD, const float* __restrict__ rtab,
    const float* __restrict__ Wrel, float* __restrict__ Rc, int NR,
    // fill
    const int* __restrict__ edge_index, const int* __restrict__ edge_type,
    const float* __restrict__ edge_norm, const int* __restrict__ entity,
    int* __restrict__ cursor, int4* __restrict__ rec, int E,
    // bprep
    const float* __restrict__ basis1, const float* __restrict__ root1,
    const float* __restrict__ basis2, const float* __restrict__ root2,
    unsigned short* __restrict__ Bp1h, unsigned short* __restrict__ Bp2h,
    int c1, int c2)     // c1=NR, c2=c1+egrid
{
    __shared__ float smem[384];
    const int b = blockIdx.x, tid = threadIdx.x;

    if (b < c1) {                        // ---- relctx ----
        float* part = smem;              // [2][128]
        float* r1s  = smem + 256;        // [128]
        int r = b;
        int o = tid & 127, q = tid >> 7;
        float s = 0.f;
        for (int j = q; j < NR; j += 2)
            s = fmaf(DAD[r * NR + j], rtab[j * 128 + o], s);
        part[q * 128 + o] = s;
        __syncthreads();
        if (tid < 128) r1s[tid] = part[tid] + part[128 + tid];
        __syncthreads();
        float s2 = 0.f;
        #pragma unroll 8
        for (int k = q * 64; k < q * 64 + 64; ++k)
            s2 = fmaf(r1s[k], Wrel[k * 128 + o], s2);
        part[q * 128 + o] = s2;
        __syncthreads();
        if (tid < 128)
            Rc[r * 128 + tid] = fmaxf(part[tid] + part[128 + tid], 0.f);
    } else if (b < c2) {                 // ---- fill: edge records ----
        int e = (b - c1) * 256 + tid;
        if (e >= E) return;
        int dst = edge_index[E + e];
        int et  = edge_type[e];
        float n = edge_norm[e];
        int src = edge_index[e];
        int ent = entity[src];
        int pos = atomicAdd(&cursor[dst], 1);
        rec[pos] = make_int4(src, ent, et, __float_as_int(n));
    } else {                             // ---- B prep (hi only) ----
        int bb = b - c2;
        int layer = bb >= 320;
        int idx = (layer ? bb - 320 : bb) * 256 + tid;
        int n = idx & 127, k = idx >> 7;
        const float* basis = layer ? basis2 : basis1;
        const float* root  = layer ? root2  : root1;
        float v = (k < 512) ? basis[((k & 3) << 14) + ((k >> 2) << 7) + n]
                            : root[((k - 512) << 7) + n];
        size_t pos = (((size_t)(k >> 3) * 128) + n) * 8 + (k & 7);
        (layer ? Bp2h : Bp1h)[pos] = f2bf(v);
    }
}

// ---------------- FUSED layer: Xout = relu([agg(X)|X] @ B + bias) ----------------
// 512 threads, 32 nodes. Gather: 32 groups x 16 lanes, one node per group.
// F32SRC=true : X rows come from f32 table Xf, gather index = rec.y (entity-
//               resolved), own-row index = entity[gn]; hi/lo made in-register.
// F32SRC=false: X rows from bf16 Xh/Xl, gather index = rec.x (graph node).
// a[b] = norm * att[et][b] computed on the fly (att is L1-resident).
template<bool F32SRC>
__global__ __launch_bounds__(512, 4) void layer_kernel(
    const unsigned short* __restrict__ Xh,    // [N,128] bf16 hi (F32SRC=false)
    const unsigned short* __restrict__ Xl,    // [N,128] bf16 lo
    const float* __restrict__ Xf,             // [*,128] f32     (F32SRC=true)
    const int* __restrict__ entity,
    const int* __restrict__ row_start,
    const int4* __restrict__ rec,             // {src, ent, et, norm}
    const float* __restrict__ att,            // [R][4]
    const unsigned short* __restrict__ Bph,   // packed [80][128][8] bf16
    const float* __restrict__ bias,
    unsigned short* __restrict__ Xoh,
    unsigned short* __restrict__ Xol,
    int N)
{
    __shared__ unsigned short Whi[64 * 32 * 8];   // 32 KB (agg part only)

    const int tid   = threadIdx.x;
    const int node0 = blockIdx.x * 32;

    // ---- phase A: gather, 1 node per 16-lane group ----
    {
        const int g = tid >> 4, l = tid & 15;     // lane l covers dims 8l..8l+7
        const int gn = node0 + g;
        const bool ok = gn < N;
        int s0 = ok ? row_start[gn] : 0;
        int s1 = ok ? row_start[gn + 1] : 0;
        float acc[8][4];                          // [local dim][basis]
        #pragma unroll
        for (int d = 0; d < 8; ++d)
            #pragma unroll
            for (int c = 0; c < 4; ++c) acc[d][c] = 0.f;

        const int se = s1 - 1;
        for (int q0 = s0; q0 < s1; q0 += 4) {
            int q1 = min(q0 + 1, se);
            int q2 = min(q0 + 2, se);
            int q3 = min(q0 + 3, se);
            int4 rA = rec[q0], rB = rec[q1], rC = rec[q2], rD = rec[q3];
            float4 tA = *(const float4*)&att[(size_t)rA.z * 4];
            float4 tB = *(const float4*)&att[(size_t)rB.z * 4];
            float4 tC = *(const float4*)&att[(size_t)rC.z * 4];
            float4 tD = *(const float4*)&att[(size_t)rD.z * 4];
            float nA = __int_as_float(rA.w), nB_ = __int_as_float(rB.w);
            float nC = __int_as_float(rC.w), nD = __int_as_float(rD.w);
            if (q0 + 1 > se) nB_ = 0.f;
            if (q0 + 2 > se) nC = 0.f;
            if (q0 + 3 > se) nD = 0.f;
            float4 aA = make_float4(nA * tA.x, nA * tA.y, nA * tA.z, nA * tA.w);
            float4 aB = make_float4(nB_ * tB.x, nB_ * tB.y, nB_ * tB.z, nB_ * tB.w);
            float4 aC = make_float4(nC * tC.x, nC * tC.y, nC * tC.z, nC * tC.w);
            float4 aD = make_float4(nD * tD.x, nD * tD.y, nD * tD.z, nD * tD.w);

            float xA[8], xB[8], xC[8], xD[8];
            if constexpr (F32SRC) {
                const float4* pA = (const float4*)&Xf[(size_t)rA.y * 128 + (l << 3)];
                const float4* pB = (const float4*)&Xf[(size_t)rB.y * 128 + (l << 3)];
                const float4* pC = (const float4*)&Xf[(size_t)rC.y * 128 + (l << 3)];
                const float4* pD = (const float4*)&Xf[(size_t)rD.y * 128 + (l << 3)];
                float4 uA0 = pA[0], uA1 = pA[1];
                float4 uB0 = pB[0], uB1 = pB[1];
                float4 uC0 = pC[0], uC1 = pC[1];
                float4 uD0 = pD[0], uD1 = pD[1];
                xA[0]=uA0.x; xA[1]=uA0.y; xA[2]=uA0.z; xA[3]=uA0.w;
                xA[4]=uA1.x; xA[5]=uA1.y; xA[6]=uA1.z; xA[7]=uA1.w;
                xB[0]=uB0.x; xB[1]=uB0.y; xB[2]=uB0.z; xB[3]=uB0.w;
                xB[4]=uB1.x; xB[5]=uB1.y; xB[6]=uB1.z; xB[7]=uB1.w;
                xC[0]=uC0.x; xC[1]=uC0.y; xC[2]=uC0.z; xC[3]=uC0.w;
                xC[4]=uC1.x; xC[5]=uC1.y; xC[6]=uC1.z; xC[7]=uC1.w;
                xD[0]=uD0.x; xD[1]=uD0.y; xD[2]=uD0.z; xD[3]=uD0.w;
                xD[4]=uD1.x; xD[5]=uD1.y; xD[6]=uD1.z; xD[7]=uD1.w;
            } else {
                s8v hA = *(const s8v*)&Xh[(size_t)rA.x * 128 + (l << 3)];
                s8v hB = *(const s8v*)&Xh[(size_t)rB.x * 128 + (l << 3)];
                s8v hC = *(const s8v*)&Xh[(size_t)rC.x * 128 + (l << 3)];
                s8v hD = *(const s8v*)&Xh[(size_t)rD.x * 128 + (l << 3)];
                #pragma unroll
                for (int d = 0; d < 8; ++d) {
                    xA[d] = bf2f((unsigned short)hA[d]);
                    xB[d] = bf2f((unsigned short)hB[d]);
                    xC[d] = bf2f((unsigned short)hC[d]);
                    xD[d] = bf2f((unsigned short)hD[d]);
                }
            }
            #pragma unroll
            for (int d = 0; d < 8; ++d) {
                acc[d][0] = fmaf(aA.x, xA[d], fmaf(aB.x, xB[d], fmaf(aC.x, xC[d], fmaf(aD.x, xD[d], acc[d][0]))));
                acc[d][1] = fmaf(aA.y, xA[d], fmaf(aB.y, xB[d], fmaf(aC.y, xC[d], fmaf(aD.y, xD[d], acc[d][1]))));
                acc[d][2] = fmaf(aA.z, xA[d], fmaf(aB.z, xB[d], fmaf(aC.z, xC[d], fmaf(aD.z, xD[d], acc[d][2]))));
                acc[d][3] = fmaf(aA.w, xA[d], fmaf(aB.w, xB[d], fmaf(aC.w, xC[d], fmaf(aD.w, xD[d], acc[d][3]))));
            }
        }
        float inv = 1.0f / fmaxf((float)(s1 - s0), 1.0f);
        #pragma unroll
        for (int f = 0; f < 4; ++f) {             // fragment kh = 4l+f
            int kh   = 4 * l + f;
            int slot = g ^ (kh & 31);
            s8v h8;
            #pragma unroll
            for (int j = 0; j < 4; ++j) {
                h8[j]     = (short)f2bf(acc[2 * f][j]     * inv);
                h8[4 + j] = (short)f2bf(acc[2 * f + 1][j] * inv);
            }
            *(s8v*)&Whi[(kh * 32 + slot) * 8] = h8;
        }
    }

    // ---- own-row X fragments direct from global (waves 0-3 only) ----
    const int lane = tid & 63, wv = tid >> 6;
    const int m    = lane & 31;
    const int kh8  = lane >> 5;
    s8v xh[8], xl[8];
    if (tid < 256) {
        const s8v z8 = {0, 0, 0, 0, 0, 0, 0, 0};
        int gn  = node0 + m;
        bool ok = gn < N;
        if constexpr (F32SRC) {
            int en = ok ? entity[gn] : 0;
            const float* base = &Xf[(size_t)en * 128];
            #pragma unroll
            for (int q = 0; q < 8; ++q) {
                int dk = 2 * q + kh8;             // == khg - 64
                const float4* p = (const float4*)&base[dk * 8];
                float4 u0 = p[0], u1 = p[1];
                float vs[8] = {u0.x, u0.y, u0.z, u0.w, u1.x, u1.y, u1.z, u1.w};
                s8v h8, l8;
                #pragma unroll
                for (int j = 0; j < 8; ++j) {
                    unsigned short h = f2bf(vs[j]);
                    h8[j] = (short)h;
                    l8[j] = (short)f2bf(vs[j] - bf2f(h));
                }
                xh[q] = h8; xl[q] = l8;
            }
        } else {
            size_t xbase = (size_t)(ok ? gn : 0) * 128;
            #pragma unroll
            for (int q = 0; q < 8; ++q) {
                int dk = 2 * q + kh8;
                xh[q] = *(const s8v*)&Xh[xbase + dk * 8];
                xl[q] = *(const s8v*)&Xl[xbase + dk * 8];
            }
        }
        if (!ok) {
            #pragma unroll
            for (int q = 0; q < 8; ++q) { xh[q] = z8; xl[q] = z8; }
        }
    }
    __syncthreads();
    if (tid >= 256) return;                       // waves 4-7 done (no more barriers)

    // ---- phase B: barrier-free MFMA stream ----
    const int c0 = wv << 5;

    f16v acc;
    #pragma unroll
    for (int i = 0; i < 16; ++i) acc[i] = 0.f;

    s8v Bb[2][4];
    auto khg_of = [&](int t) {
        return (t < 8) ? (64 + 2 * t + kh8) : (2 * (t - 8) + kh8);
    };
    auto loadB4 = [&](int g, int buf) {
        #pragma unroll
        for (int q = 0; q < 4; ++q) {
            int khg = khg_of(g * 4 + q);
            size_t off = ((size_t)khg * 128 + c0 + m) * 8;
            Bb[buf][q] = *(const s8v*)&Bph[off];
        }
    };
    loadB4(0, 0);

    #pragma unroll
    for (int g = 0; g < 10; ++g) {
        int buf = g & 1;
        if (g < 9) loadB4(g + 1, buf ^ 1);
        #pragma unroll
        for (int q = 0; q < 4; ++q) {
            int t = g * 4 + q;
            if (t < 8) {
                acc = __builtin_amdgcn_mfma_f32_32x32x16_bf16(xl[t], Bb[buf][q], acc, 0, 0, 0);
                acc = __builtin_amdgcn_mfma_f32_32x32x16_bf16(xh[t], Bb[buf][q], acc, 0, 0, 0);
            } else {
                int khg  = 2 * (t - 8) + kh8;
                int slot = m ^ (khg & 31);
                s8v aH = *(const s8v*)&Whi[(khg * 32 + slot) * 8];
                acc = __builtin_amdgcn_mfma_f32_32x32x16_bf16(aH, Bb[buf][q], acc, 0, 0, 0);
            }
        }
    }

    // epilogue: 32x32 C/D: col = lane&31, row = (reg&3) + 8*(reg>>2) + 4*(lane>>5)
    int gc = c0 + m;
    float bv = bias[gc];
    const int rbase = kh8 << 2;
    #pragma unroll
    for (int reg = 0; reg < 16; ++reg) {
        int gr = node0 + rbase + (reg & 3) + ((reg >> 2) << 3);
        if (gr < N) {
            float v = fmaxf(acc[reg] + bv, 0.f);
            unsigned short h = f2bf(v);
            Xoh[(size_t)gr * 128 + gc] = h;
            Xol[(size_t)gr * 128 + gc] = f2bf(v - bf2f(h));
        }
    }
}

// ---------------- gated output: 8 samples per block ----------------
__global__ __launch_bounds__(256) void output_kernel(
    const int* __restrict__ samples,
    const float* __restrict__ gate_e,
    const float* __restrict__ gate_r,
    const float* __restrict__ ent_emb,
    const float* __restrict__ rel_emb,
    const unsigned short* __restrict__ ctx2h,
    const unsigned short* __restrict__ ctx2l,
    const float* __restrict__ relctx,
    float* __restrict__ out, int S)
{
    const int p   = blockIdx.y;
    const int o   = threadIdx.x & 127;
    const int sub = threadIdx.x >> 7;
    const float g = (p == 1) ? 1.0f / (1.0f + __expf(-gate_r[o]))
                             : 1.0f / (1.0f + __expf(-gate_e[o]));
    const int s0 = blockIdx.x * 8 + sub;
    #pragma unroll
    for (int k = 0; k < 4; ++k) {
        int s = s0 + k * 2;
        if (s >= S) break;
        float v;
        if (p == 1) {
            int idx = samples[s * 3 + 1];
            v = g * rel_emb[idx * 128 + o] + (1.0f - g) * relctx[idx * 128 + o];
        } else {
            int idx = samples[s * 3 + (p == 0 ? 0 : 2)];
            float c = bf2f(ctx2h[(size_t)idx * 128 + o]) + bf2f(ctx2l[(size_t)idx * 128 + o]);
            v = g * ent_emb[(size_t)idx * 128 + o] + (1.0f - g) * c;
        }
        out[(size_t)p * S * 128 + (size_t)s * 128 + o] = v;
    }
}

extern "C" void kernel_launch(void* const* d_in, const int* in_sizes, int n_in,
                              void* d_out, int out_size, void* d_ws, size_t ws_size,
                              hipStream_t stream)
{
    const int*   entity     = (const int*)d_in[0];
    const int*   edge_index = (const int*)d_in[1];
    const int*   edge_type  = (const int*)d_in[2];
    const float* edge_norm  = (const float*)d_in[3];
    const int*   samples    = (const int*)d_in[4];
    const float* DAD        = (const float*)d_in[5];
    const float* ent_emb    = (const float*)d_in[6];
    const float* rel_emb    = (const float*)d_in[7];
    const float* ent_tab    = (const float*)d_in[8];
    const float* rel_tab    = (const float*)d_in[9];
    const float* Wrel       = (const float*)d_in[10];
    const float* gate_e     = (const float*)d_in[11];
    const float* gate_r     = (const float*)d_in[12];
    const float* basis1     = (const float*)d_in[13];
    const float* att1       = (const float*)d_in[14];
    const float* root1      = (const float*)d_in[15];
    const float* bias1      = (const float*)d_in[16];
    const float* basis2     = (const float*)d_in[17];
    const float* att2       = (const float*)d_in[18];
    const float* root2      = (const float*)d_in[19];
    const float* bias2      = (const float*)d_in[20];

    const int N  = in_sizes[0];        // 50000
    const int E  = in_sizes[2];        // 200000
    const int S  = in_sizes[4] / 3;    // 20000
    const int NR = in_sizes[9] / 128;  // 200

    unsigned short* X1h = (unsigned short*)d_ws;       // [N,128] bf16 (layer1 out)
    unsigned short* X1l = X1h + (size_t)N * 128;
    unsigned short* C2h = X1l + (size_t)N * 128;       // [N,128] bf16 (layer2 out)
    unsigned short* C2l = C2h + (size_t)N * 128;
    int4*  rec     = (int4*)(C2l + (size_t)N * 128);   // [E+4] {src,ent,et,norm}
    float* Rc      = (float*)(rec + (E + 4));          // [NR,128]
    int*   deg     = (int*)(Rc + (size_t)NR * 128);    // [N]
    int*   rstart  = deg + N;                          // [N+1]
    int*   cursor  = rstart + N + 1;                   // [N]
    int*   btot    = cursor + N;                       // [64]
    uintptr_t bt   = ((uintptr_t)(btot + 64) + 15) & ~(uintptr_t)15;
    unsigned short* Bp1h = (unsigned short*)bt;        // [80*128*8]
    unsigned short* Bp2h = Bp1h + 80 * 128 * 8;

    const int egrid = (E + 255) / 256;
    const int lgrid = (N + 31) / 32;
    const int nB    = (N + 1023) / 1024;
    const int c1 = NR;
    const int c2 = c1 + egrid;
    const int mgrid = c2 + 640;

    hipMemsetAsync(deg, 0, (size_t)N * sizeof(int), stream);
    hist_kernel<<<egrid, 256, 0, stream>>>(edge_index, deg, E);
    scanA_kernel<<<nB, 1024, 0, stream>>>(deg, rstart, btot, N);
    scanC_kernel<<<nB, 1024, 0, stream>>>(rstart, cursor, btot, nB, N);
    mega_kernel<<<mgrid, 256, 0, stream>>>(
        DAD, rel_tab, Wrel, Rc, NR,
        edge_index, edge_type, edge_norm, entity, cursor, rec, E,
        basis1, root1, basis2, root2, Bp1h, Bp2h,
        c1, c2);

    // ---- layer 1: X1 = relu([agg(X0)|X0] @ W1), X0 = tab[entity] read as f32 ----
    layer_kernel<true><<<lgrid, 512, 0, stream>>>(
        nullptr, nullptr, ent_tab, entity, rstart, rec, att1,
        Bp1h, bias1, X1h, X1l, N);
    // ---- layer 2: C2 = relu([agg(X1)|X1] @ W2) ----
    layer_kernel<false><<<lgrid, 512, 0, stream>>>(
        X1h, X1l, nullptr, nullptr, rstart, rec, att2,
        Bp2h, bias2, C2h, C2l, N);

    // ---- gated output ----
    output_kernel<<<dim3((S + 7) / 8, 3), 256, 0, stream>>>(
        samples, gate_e, gate_r, ent_emb, rel_emb, C2h, C2l, Rc, (float*)d_out, S);
}

// Round 9
// 289.926 us; speedup vs baseline: 1.0875x; 1.0875x over previous
//
#include <hip/hip_runtime.h>
#include <hip/hip_bf16.h>

typedef short s8v  __attribute__((ext_vector_type(8)));
typedef float f16v __attribute__((ext_vector_type(16)));

__device__ __forceinline__ unsigned short f2bf(float x) {   // RTN-even
    unsigned u = __float_as_uint(x);
    unsigned r = ((u >> 16) & 1u) + 0x7FFFu;
    return (unsigned short)((u + r) >> 16);
}
__device__ __forceinline__ float bf2f(unsigned short h) {
    return __uint_as_float(((unsigned)h) << 16);
}

// ---------------- hist only (critical chain head, keep it tiny) ----------------
__global__ __launch_bounds__(256) void hist_kernel(
    const int* __restrict__ edge_index, int* __restrict__ deg, int E)
{
    int e = blockIdx.x * 256 + threadIdx.x;
    if (e < E) atomicAdd(&deg[edge_index[E + e]], 1);
}

// ---------------- CSR scan ----------------
__global__ __launch_bounds__(1024) void scanA_kernel(
    const int* __restrict__ deg, int* __restrict__ row_start,
    int* __restrict__ btot, int N)
{
    __shared__ int wtot[16];
    __shared__ int woff[16];
    const int tid = threadIdx.x, lane = tid & 63, wid = tid >> 6;
    int i = blockIdx.x * 1024 + tid;
    int v = (i < N) ? deg[i] : 0;
    int x = v;
    #pragma unroll
    for (int d = 1; d < 64; d <<= 1) {
        int t = __shfl_up(x, d, 64);
        if (lane >= d) x += t;
    }
    if (lane == 63) wtot[wid] = x;
    __syncthreads();
    if (wid == 0 && lane < 16) {
        int s = wtot[lane];
        int y = s;
        #pragma unroll
        for (int d = 1; d < 16; d <<= 1) {
            int t = __shfl_up(y, d, 16);
            if (lane >= d) y += t;
        }
        woff[lane] = y - s;
        if (lane == 15) btot[blockIdx.x] = y;
    }
    __syncthreads();
    if (i < N) row_start[i] = woff[wid] + (x - v);
}

// scanC with scanB inlined: every block redundantly wave-scans the <=64
// block totals (cheap), then applies its own exclusive offset.
__global__ __launch_bounds__(1024) void scanC_kernel(
    int* __restrict__ row_start, int* __restrict__ cursor,
    const int* __restrict__ btot, int nB, int N)
{
    __shared__ int incl[64];
    const int tid = threadIdx.x;
    if (tid < 64) {
        int v = (tid < nB) ? btot[tid] : 0;
        int x = v;
        #pragma unroll
        for (int d = 1; d < 64; d <<= 1) {
            int t = __shfl_up(x, d, 64);
            if (tid >= d) x += t;
        }
        incl[tid] = x;
    }
    __syncthreads();
    int off = (blockIdx.x == 0) ? 0 : incl[blockIdx.x - 1];
    int i = blockIdx.x * 1024 + tid;
    if (i < N) {
        int r = row_start[i] + off;
        row_start[i] = r;
        cursor[i]    = r;
    }
    if (blockIdx.x == (unsigned)(nB - 1) && tid == 0)
        row_start[N] = incl[nB - 1];
}

// ---------------- mega: relctx | fill(16B records) | X0 hi/lo | bprep ----------------
// fill: ONE aligned 16B record per edge {src, et, norm, 0} (no partial-line
// write amplification). X0 = bf16 hi/lo of tab[entity] IS materialized: the
// bf16 table (12.8MB) roughly halves gather L2 misses vs f32 (measured r7:
// f32 gather = 80MB FETCH, +31us/layer).
__global__ __launch_bounds__(256) void mega_kernel(
    // relctx
    const float* __restrict__ DAD, const float* __restrict__ rtab,
    const float* __restrict__ Wrel, float* __restrict__ Rc, int NR,
    // fill
    const int* __restrict__ edge_index, const int* __restrict__ edge_type,
    const float* __restrict__ edge_norm,
    int* __restrict__ cursor, int4* __restrict__ rec, int E,
    // x0
    const float* __restrict__ tab, const int* __restrict__ entity,
    unsigned short* __restrict__ X0h, unsigned short* __restrict__ X0l, int N,
    // bprep
    const float* __restrict__ basis1, const float* __restrict__ root1,
    const float* __restrict__ basis2, const float* __restrict__ root2,
    unsigned short* __restrict__ Bp1h, unsigned short* __restrict__ Bp2h,
    int c1, int c2, int c3)     // c1=NR, c2=c1+egrid, c3=c2+x0blocks
{
    __shared__ float smem[384];
    const int b = blockIdx.x, tid = threadIdx.x;

    if (b < c1) {                        // ---- relctx ----
        float* part = smem;              // [2][128]
        float* r1s  = smem + 256;        // [128]
        int r = b;
        int o = tid & 127, q = tid >> 7;
        float s = 0.f;
        for (int j = q; j < NR; j += 2)
            s = fmaf(DAD[r * NR + j], rtab[j * 128 + o], s);
        part[q * 128 + o] = s;
        __syncthreads();
        if (tid < 128) r1s[tid] = part[tid] + part[128 + tid];
        __syncthreads();
        float s2 = 0.f;
        #pragma unroll 8
        for (int k = q * 64; k < q * 64 + 64; ++k)
            s2 = fmaf(r1s[k], Wrel[k * 128 + o], s2);
        part[q * 128 + o] = s2;
        __syncthreads();
        if (tid < 128)
            Rc[r * 128 + tid] = fmaxf(part[tid] + part[128 + tid], 0.f);
    } else if (b < c2) {                 // ---- fill: edge records ----
        int e = (b - c1) * 256 + tid;
        if (e >= E) return;
        int dst = edge_index[E + e];
        int et  = edge_type[e];
        float n = edge_norm[e];
        int src = edge_index[e];
        int pos = atomicAdd(&cursor[dst], 1);
        rec[pos] = make_int4(src, et, __float_as_int(n), 0);
    } else if (b < c3) {                 // ---- X0 = tab[entity] hi/lo ----
        int idx = (b - c2) * 256 + tid;  // 8 dims / thread (2 indep float4)
        int nn = idx >> 4, part = idx & 15;
        if (nn < N) {
            int src = entity[nn];
            const float4* sp = (const float4*)&tab[(size_t)src * 128 + part * 8];
            float4 v0 = sp[0], v1 = sp[1];
            float vs[8] = {v0.x, v0.y, v0.z, v0.w, v1.x, v1.y, v1.z, v1.w};
            s8v h8, l8;
            #pragma unroll
            for (int j = 0; j < 8; ++j) {
                unsigned short h = f2bf(vs[j]);
                h8[j] = (short)h;
                l8[j] = (short)f2bf(vs[j] - bf2f(h));
            }
            *(s8v*)&X0h[(size_t)nn * 128 + part * 8] = h8;
            *(s8v*)&X0l[(size_t)nn * 128 + part * 8] = l8;
        }
    } else {                             // ---- B prep (hi only) ----
        int bb = b - c3;
        int layer = bb >= 320;
        int idx = (layer ? bb - 320 : bb) * 256 + tid;
        int n = idx & 127, k = idx >> 7;
        const float* basis = layer ? basis2 : basis1;
        const float* root  = layer ? root2  : root1;
        float v = (k < 512) ? basis[((k & 3) << 14) + ((k >> 2) << 7) + n]
                            : root[((k - 512) << 7) + n];
        size_t pos = (((size_t)(k >> 3) * 128) + n) * 8 + (k & 7);
        (layer ? Bp2h : Bp1h)[pos] = f2bf(v);
    }
}

// LDS slot permutation for Whi: slot = (n + (kh>>2) + ((kh&3)<<3)) & 31.
// Write side (lane l writes kh=4l+f for node g): bank = ((g+l+8f)*4)%32
// varies fully with l (old XOR gave only 2 bank-quads per 16-lane group ->
// 1.2M conflicts/dispatch). Read side: slot = m + const (bijective, clean).
__device__ __forceinline__ int wslot(int n, int kh) {
    return (n + (kh >> 2) + ((kh & 3) << 3)) & 31;
}

// ---------------- FUSED layer: Xout = relu([agg(X)|X] @ B + bias) ----------------
// 512 threads, 32 nodes. Gather: 32 groups x 16 lanes, one node per group.
// a[b] = norm * att[et][b] computed on the fly (att is L1-resident).
// Waves 4-7 exit after the single barrier; waves 0-3 run the barrier-free
// MFMA stream (B double-buffered global->reg, own-row X direct from global).
__global__ __launch_bounds__(512, 4) void layer_kernel(
    const unsigned short* __restrict__ Xh,    // [N,128] bf16 hi
    const unsigned short* __restrict__ Xl,    // [N,128] bf16 lo
    const int* __restrict__ row_start,
    const int4* __restrict__ rec,             // {src, et, norm, 0}
    const float* __restrict__ att,            // [R][4]
    const unsigned short* __restrict__ Bph,   // packed [80][128][8] bf16
    const float* __restrict__ bias,
    unsigned short* __restrict__ Xoh,
    unsigned short* __restrict__ Xol,
    int N)
{
    __shared__ unsigned short Whi[64 * 32 * 8];   // 32 KB (agg part only)

    const int tid   = threadIdx.x;
    const int node0 = blockIdx.x * 32;

    // ---- phase A: gather, 1 node per 16-lane group ----
    {
        const int g = tid >> 4, l = tid & 15;     // lane l covers dims 8l..8l+7
        const int gn = node0 + g;
        const bool ok = gn < N;
        int s0 = ok ? row_start[gn] : 0;
        int s1 = ok ? row_start[gn + 1] : 0;
        float acc[8][4];                          // [local dim][basis]
        #pragma unroll
        for (int d = 0; d < 8; ++d)
            #pragma unroll
            for (int c = 0; c < 4; ++c) acc[d][c] = 0.f;

        const int se = s1 - 1;
        for (int q0 = s0; q0 < s1; q0 += 4) {
            int q1 = min(q0 + 1, se);
            int q2 = min(q0 + 2, se);
            int q3 = min(q0 + 3, se);
            int4 rA = rec[q0], rB = rec[q1], rC = rec[q2], rD = rec[q3];
            float4 tA = *(const float4*)&att[(size_t)rA.y * 4];
            float4 tB = *(const float4*)&att[(size_t)rB.y * 4];
            float4 tC = *(const float4*)&att[(size_t)rC.y * 4];
            float4 tD = *(const float4*)&att[(size_t)rD.y * 4];
            float nA = __int_as_float(rA.z), nB_ = __int_as_float(rB.z);
            float nC = __int_as_float(rC.z), nD = __int_as_float(rD.z);
            if (q0 + 1 > se) nB_ = 0.f;
            if (q0 + 2 > se) nC = 0.f;
            if (q0 + 3 > se) nD = 0.f;
            float4 aA = make_float4(nA * tA.x, nA * tA.y, nA * tA.z, nA * tA.w);
            float4 aB = make_float4(nB_ * tB.x, nB_ * tB.y, nB_ * tB.z, nB_ * tB.w);
            float4 aC = make_float4(nC * tC.x, nC * tC.y, nC * tC.z, nC * tC.w);
            float4 aD = make_float4(nD * tD.x, nD * tD.y, nD * tD.z, nD * tD.w);
            s8v hA = *(const s8v*)&Xh[(size_t)rA.x * 128 + (l << 3)];
            s8v hB = *(const s8v*)&Xh[(size_t)rB.x * 128 + (l << 3)];
            s8v hC = *(const s8v*)&Xh[(size_t)rC.x * 128 + (l << 3)];
            s8v hD = *(const s8v*)&Xh[(size_t)rD.x * 128 + (l << 3)];
            #pragma unroll
            for (int d = 0; d < 8; ++d) {
                float xA = bf2f((unsigned short)hA[d]);
                float xB = bf2f((unsigned short)hB[d]);
                float xC = bf2f((unsigned short)hC[d]);
                float xD = bf2f((unsigned short)hD[d]);
                acc[d][0] = fmaf(aA.x, xA, fmaf(aB.x, xB, fmaf(aC.x, xC, fmaf(aD.x, xD, acc[d][0]))));
                acc[d][1] = fmaf(aA.y, xA, fmaf(aB.y, xB, fmaf(aC.y, xC, fmaf(aD.y, xD, acc[d][1]))));
                acc[d][2] = fmaf(aA.z, xA, fmaf(aB.z, xB, fmaf(aC.z, xC, fmaf(aD.z, xD, acc[d][2]))));
                acc[d][3] = fmaf(aA.w, xA, fmaf(aB.w, xB, fmaf(aC.w, xC, fmaf(aD.w, xD, acc[d][3]))));
            }
        }
        float inv = 1.0f / fmaxf((float)(s1 - s0), 1.0f);
        #pragma unroll
        for (int f = 0; f < 4; ++f) {             // fragment kh = 4l+f
            int kh   = 4 * l + f;
            int slot = wslot(g, kh);
            s8v h8;
            #pragma unroll
            for (int j = 0; j < 4; ++j) {
                h8[j]     = (short)f2bf(acc[2 * f][j]     * inv);
                h8[4 + j] = (short)f2bf(acc[2 * f + 1][j] * inv);
            }
            *(s8v*)&Whi[(kh * 32 + slot) * 8] = h8;
        }
    }

    // ---- own-row X fragments direct from global (waves 0-3 only) ----
    const int lane = tid & 63, wv = tid >> 6;
    const int m    = lane & 31;
    const int kh8  = lane >> 5;
    s8v xh[8], xl[8];
    if (tid < 256) {
        const s8v z8 = {0, 0, 0, 0, 0, 0, 0, 0};
        int gn  = node0 + m;
        bool ok = gn < N;
        size_t xbase = (size_t)(ok ? gn : 0) * 128;
        #pragma unroll
        for (int q = 0; q < 8; ++q) {
            int dk = 2 * q + kh8;                 // == khg - 64
            xh[q] = *(const s8v*)&Xh[xbase + dk * 8];
            xl[q] = *(const s8v*)&Xl[xbase + dk * 8];
        }
        if (!ok) {
            #pragma unroll
            for (int q = 0; q < 8; ++q) { xh[q] = z8; xl[q] = z8; }
        }
    }
    __syncthreads();
    if (tid >= 256) return;                       // waves 4-7 done (no more barriers)

    // ---- phase B: barrier-free MFMA stream ----
    // X-part first (t=0..7, regs just loaded, freed early), then agg from LDS.
    const int c0 = wv << 5;

    f16v acc;
    #pragma unroll
    for (int i = 0; i < 16; ++i) acc[i] = 0.f;

    s8v Bb[2][4];
    auto khg_of = [&](int t) {
        return (t < 8) ? (64 + 2 * t + kh8) : (2 * (t - 8) + kh8);
    };
    auto loadB4 = [&](int g, int buf) {
        #pragma unroll
        for (int q = 0; q < 4; ++q) {
            int khg = khg_of(g * 4 + q);
            size_t off = ((size_t)khg * 128 + c0 + m) * 8;
            Bb[buf][q] = *(const s8v*)&Bph[off];
        }
    };
    loadB4(0, 0);

    #pragma unroll
    for (int g = 0; g < 10; ++g) {
        int buf = g & 1;
        if (g < 9) loadB4(g + 1, buf ^ 1);
        #pragma unroll
        for (int q = 0; q < 4; ++q) {
            int t = g * 4 + q;
            if (t < 8) {
                acc = __builtin_amdgcn_mfma_f32_32x32x16_bf16(xl[t], Bb[buf][q], acc, 0, 0, 0);
                acc = __builtin_amdgcn_mfma_f32_32x32x16_bf16(xh[t], Bb[buf][q], acc, 0, 0, 0);
            } else {
                int khg  = 2 * (t - 8) + kh8;
                int slot = wslot(m, khg);
                s8v aH = *(const s8v*)&Whi[(khg * 32 + slot) * 8];
                acc = __builtin_amdgcn_mfma_f32_32x32x16_bf16(aH, Bb[buf][q], acc, 0, 0, 0);
            }
        }
    }

    // epilogue: 32x32 C/D: col = lane&31, row = (reg&3) + 8*(reg>>2) + 4*(lane>>5)
    int gc = c0 + m;
    float bv = bias[gc];
    const int rbase = kh8 << 2;
    #pragma unroll
    for (int reg = 0; reg < 16; ++reg) {
        int gr = node0 + rbase + (reg & 3) + ((reg >> 2) << 3);
        if (gr < N) {
            float v = fmaxf(acc[reg] + bv, 0.f);
            unsigned short h = f2bf(v);
            Xoh[(size_t)gr * 128 + gc] = h;
            Xol[(size_t)gr * 128 + gc] = f2bf(v - bf2f(h));
        }
    }
}

// ---------------- gated output: 8 samples per block ----------------
__global__ __launch_bounds__(256) void output_kernel(
    const int* __restrict__ samples,
    const float* __restrict__ gate_e,
    const float* __restrict__ gate_r,
    const float* __restrict__ ent_emb,
    const float* __restrict__ rel_emb,
    const unsigned short* __restrict__ ctx2h,
    const unsigned short* __restrict__ ctx2l,
    const float* __restrict__ relctx,
    float* __restrict__ out, int S)
{
    const int p   = blockIdx.y;
    const int o   = threadIdx.x & 127;
    const int sub = threadIdx.x >> 7;
    const float g = (p == 1) ? 1.0f / (1.0f + __expf(-gate_r[o]))
                             : 1.0f / (1.0f + __expf(-gate_e[o]));
    const int s0 = blockIdx.x * 8 + sub;
    #pragma unroll
    for (int k = 0; k < 4; ++k) {
        int s = s0 + k * 2;
        if (s >= S) break;
        float v;
        if (p == 1) {
            int idx = samples[s * 3 + 1];
            v = g * rel_emb[idx * 128 + o] + (1.0f - g) * relctx[idx * 128 + o];
        } else {
            int idx = samples[s * 3 + (p == 0 ? 0 : 2)];
            float c = bf2f(ctx2h[(size_t)idx * 128 + o]) + bf2f(ctx2l[(size_t)idx * 128 + o]);
            v = g * ent_emb[(size_t)idx * 128 + o] + (1.0f - g) * c;
        }
        out[(size_t)p * S * 128 + (size_t)s * 128 + o] = v;
    }
}

extern "C" void kernel_launch(void* const* d_in, const int* in_sizes, int n_in,
                              void* d_out, int out_size, void* d_ws, size_t ws_size,
                              hipStream_t stream)
{
    const int*   entity     = (const int*)d_in[0];
    const int*   edge_index = (const int*)d_in[1];
    const int*   edge_type  = (const int*)d_in[2];
    const float* edge_norm  = (const float*)d_in[3];
    const int*   samples    = (const int*)d_in[4];
    const float* DAD        = (const float*)d_in[5];
    const float* ent_emb    = (const float*)d_in[6];
    const float* rel_emb    = (const float*)d_in[7];
    const float* ent_tab    = (const float*)d_in[8];
    const float* rel_tab    = (const float*)d_in[9];
    const float* Wrel       = (const float*)d_in[10];
    const float* gate_e     = (const float*)d_in[11];
    const float* gate_r     = (const float*)d_in[12];
    const float* basis1     = (const float*)d_in[13];
    const float* att1       = (const float*)d_in[14];
    const float* root1      = (const float*)d_in[15];
    const float* bias1      = (const float*)d_in[16];
    const float* basis2     = (const float*)d_in[17];
    const float* att2       = (const float*)d_in[18];
    const float* root2      = (const float*)d_in[19];
    const float* bias2      = (const float*)d_in[20];

    const int N  = in_sizes[0];        // 50000
    const int E  = in_sizes[2];        // 200000
    const int S  = in_sizes[4] / 3;    // 20000
    const int NR = in_sizes[9] / 128;  // 200

    unsigned short* X0h = (unsigned short*)d_ws;       // [N,128] bf16
    unsigned short* X0l = X0h + (size_t)N * 128;
    unsigned short* X1h = X0l + (size_t)N * 128;       // layer1 out
    unsigned short* X1l = X1h + (size_t)N * 128;
    int4*  rec     = (int4*)(X1l + (size_t)N * 128);   // [E+4] {src,et,norm,0}
    float* Rc      = (float*)(rec + (E + 4));          // [NR,128]
    int*   deg     = (int*)(Rc + (size_t)NR * 128);    // [N]
    int*   rstart  = deg + N;                          // [N+1]
    int*   cursor  = rstart + N + 1;                   // [N]
    int*   btot    = cursor + N;                       // [64]
    uintptr_t bt   = ((uintptr_t)(btot + 64) + 15) & ~(uintptr_t)15;
    unsigned short* Bp1h = (unsigned short*)bt;        // [80*128*8]
    unsigned short* Bp2h = Bp1h + 80 * 128 * 8;

    const int egrid = (E + 255) / 256;
    const int lgrid = (N + 31) / 32;
    const int nB    = (N + 1023) / 1024;
    const int x0blocks = (N * 16 + 255) / 256;
    const int c1 = NR;
    const int c2 = c1 + egrid;
    const int c3 = c2 + x0blocks;
    const int mgrid = c3 + 640;

    hipMemsetAsync(deg, 0, (size_t)N * sizeof(int), stream);
    hist_kernel<<<egrid, 256, 0, stream>>>(edge_index, deg, E);
    scanA_kernel<<<nB, 1024, 0, stream>>>(deg, rstart, btot, N);
    scanC_kernel<<<nB, 1024, 0, stream>>>(rstart, cursor, btot, nB, N);
    mega_kernel<<<mgrid, 256, 0, stream>>>(
        DAD, rel_tab, Wrel, Rc, NR,
        edge_index, edge_type, edge_norm, cursor, rec, E,
        ent_tab, entity, X0h, X0l, N,
        basis1, root1, basis2, root2, Bp1h, Bp2h,
        c1, c2, c3);

    // ---- layer 1: X1 = relu([agg(X0)|X0] @ W1) ----
    layer_kernel<<<lgrid, 512, 0, stream>>>(X0h, X0l, rstart, rec, att1,
                                            Bp1h, bias1, X1h, X1l, N);
    // ---- layer 2: X0 = relu([agg(X1)|X1] @ W2)  (overwrites X0 buffers) ----
    layer_kernel<<<lgrid, 512, 0, stream>>>(X1h, X1l, rstart, rec, att2,
                                            Bp2h, bias2, X0h, X0l, N);

    // ---- gated output ----
    output_kernel<<<dim3((S + 7) / 8, 3), 256, 0, stream>>>(
        samples, gate_e, gate_r, ent_emb, rel_emb, X0h, X0l, Rc, (float*)d_out, S);
}

// Round 13
// 279.697 us; speedup vs baseline: 1.1273x; 1.0366x over previous
//
#include <hip/hip_runtime.h>
#include <hip/hip_bf16.h>

typedef short s8v  __attribute__((ext_vector_type(8)));
typedef float f16v __attribute__((ext_vector_type(16)));
typedef float f2v  __attribute__((ext_vector_type(2)));

__device__ __forceinline__ unsigned short f2bf(float x) {   // RTN-even (scalar fallback)
    unsigned u = __float_as_uint(x);
    unsigned r = ((u >> 16) & 1u) + 0x7FFFu;
    return (unsigned short)((u + r) >> 16);
}
__device__ __forceinline__ float bf2f(unsigned short h) {
    return __uint_as_float(((unsigned)h) << 16);
}
// HW packed convert: lo16 = bf16(a), hi16 = bf16(b). Same instr HIP's
// __float2bfloat16 uses on gfx950 (RNE) -> numerics identical to f2bf.
__device__ __forceinline__ unsigned cvt2(float a, float b) {
    unsigned r;
    asm("v_cvt_pk_bf16_f32 %0, %1, %2" : "=v"(r) : "v"(a), "v"(b));
    return r;
}

// ---------------- hist only (critical chain head, keep it tiny) ----------------
__global__ __launch_bounds__(256) void hist_kernel(
    const int* __restrict__ edge_index, int* __restrict__ deg, int E)
{
    int e = blockIdx.x * 256 + threadIdx.x;
    if (e < E) atomicAdd(&deg[edge_index[E + e]], 1);
}

// ---------------- CSR scan ----------------
__global__ __launch_bounds__(1024) void scanA_kernel(
    const int* __restrict__ deg, int* __restrict__ row_start,
    int* __restrict__ btot, int N)
{
    __shared__ int wtot[16];
    __shared__ int woff[16];
    const int tid = threadIdx.x, lane = tid & 63, wid = tid >> 6;
    int i = blockIdx.x * 1024 + tid;
    int v = (i < N) ? deg[i] : 0;
    int x = v;
    #pragma unroll
    for (int d = 1; d < 64; d <<= 1) {
        int t = __shfl_up(x, d, 64);
        if (lane >= d) x += t;
    }
    if (lane == 63) wtot[wid] = x;
    __syncthreads();
    if (wid == 0 && lane < 16) {
        int s = wtot[lane];
        int y = s;
        #pragma unroll
        for (int d = 1; d < 16; d <<= 1) {
            int t = __shfl_up(y, d, 16);
            if (lane >= d) y += t;
        }
        woff[lane] = y - s;
        if (lane == 15) btot[blockIdx.x] = y;
    }
    __syncthreads();
    if (i < N) row_start[i] = woff[wid] + (x - v);
}

// scanC with scanB inlined: every block redundantly wave-scans the <=64
// block totals (cheap), then applies its own exclusive offset.
__global__ __launch_bounds__(1024) void scanC_kernel(
    int* __restrict__ row_start, int* __restrict__ cursor,
    const int* __restrict__ btot, int nB, int N)
{
    __shared__ int incl[64];
    const int tid = threadIdx.x;
    if (tid < 64) {
        int v = (tid < nB) ? btot[tid] : 0;
        int x = v;
        #pragma unroll
        for (int d = 1; d < 64; d <<= 1) {
            int t = __shfl_up(x, d, 64);
            if (tid >= d) x += t;
        }
        incl[tid] = x;
    }
    __syncthreads();
    int off = (blockIdx.x == 0) ? 0 : incl[blockIdx.x - 1];
    int i = blockIdx.x * 1024 + tid;
    if (i < N) {
        int r = row_start[i] + off;
        row_start[i] = r;
        cursor[i]    = r;
    }
    if (blockIdx.x == (unsigned)(nB - 1) && tid == 0)
        row_start[N] = incl[nB - 1];
}

// ---------------- mega: relctx | fill(16B records) | X0 hi/lo | bprep ----------------
__global__ __launch_bounds__(256) void mega_kernel(
    // relctx
    const float* __restrict__ DAD, const float* __restrict__ rtab,
    const float* __restrict__ Wrel, float* __restrict__ Rc, int NR,
    // fill
    const int* __restrict__ edge_index, const int* __restrict__ edge_type,
    const float* __restrict__ edge_norm,
    int* __restrict__ cursor, int4* __restrict__ rec, int E,
    // x0
    const float* __restrict__ tab, const int* __restrict__ entity,
    unsigned short* __restrict__ X0h, unsigned short* __restrict__ X0l, int N,
    // bprep
    const float* __restrict__ basis1, const float* __restrict__ root1,
    const float* __restrict__ basis2, const float* __restrict__ root2,
    unsigned short* __restrict__ Bp1h, unsigned short* __restrict__ Bp2h,
    int c1, int c2, int c3)     // c1=NR, c2=c1+egrid, c3=c2+x0blocks
{
    __shared__ float smem[384];
    const int b = blockIdx.x, tid = threadIdx.x;

    if (b < c1) {                        // ---- relctx ----
        float* part = smem;              // [2][128]
        float* r1s  = smem + 256;        // [128]
        int r = b;
        int o = tid & 127, q = tid >> 7;
        float s = 0.f;
        for (int j = q; j < NR; j += 2)
            s = fmaf(DAD[r * NR + j], rtab[j * 128 + o], s);
        part[q * 128 + o] = s;
        __syncthreads();
        if (tid < 128) r1s[tid] = part[tid] + part[128 + tid];
        __syncthreads();
        float s2 = 0.f;
        #pragma unroll 8
        for (int k = q * 64; k < q * 64 + 64; ++k)
            s2 = fmaf(r1s[k], Wrel[k * 128 + o], s2);
        part[q * 128 + o] = s2;
        __syncthreads();
        if (tid < 128)
            Rc[r * 128 + tid] = fmaxf(part[tid] + part[128 + tid], 0.f);
    } else if (b < c2) {                 // ---- fill: edge records ----
        int e = (b - c1) * 256 + tid;
        if (e >= E) return;
        int dst = edge_index[E + e];
        int et  = edge_type[e];
        float n = edge_norm[e];
        int src = edge_index[e];
        int pos = atomicAdd(&cursor[dst], 1);
        rec[pos] = make_int4(src, et, __float_as_int(n), 0);
    } else if (b < c3) {                 // ---- X0 = tab[entity] hi/lo (pk-convert) ----
        int idx = (b - c2) * 256 + tid;  // 8 dims / thread
        int nn = idx >> 4, part = idx & 15;
        if (nn < N) {
            int src = entity[nn];
            const float4* sp = (const float4*)&tab[(size_t)src * 128 + part * 8];
            float4 v0 = sp[0], v1 = sp[1];
            unsigned h0 = cvt2(v0.x, v0.y);
            unsigned h1 = cvt2(v0.z, v0.w);
            unsigned h2 = cvt2(v1.x, v1.y);
            unsigned h3 = cvt2(v1.z, v1.w);
            unsigned l0 = cvt2(v0.x - __uint_as_float(h0 << 16), v0.y - __uint_as_float(h0 & 0xFFFF0000u));
            unsigned l1 = cvt2(v0.z - __uint_as_float(h1 << 16), v0.w - __uint_as_float(h1 & 0xFFFF0000u));
            unsigned l2 = cvt2(v1.x - __uint_as_float(h2 << 16), v1.y - __uint_as_float(h2 & 0xFFFF0000u));
            unsigned l3 = cvt2(v1.z - __uint_as_float(h3 << 16), v1.w - __uint_as_float(h3 & 0xFFFF0000u));
            *(uint4*)&X0h[(size_t)nn * 128 + part * 8] = make_uint4(h0, h1, h2, h3);
            *(uint4*)&X0l[(size_t)nn * 128 + part * 8] = make_uint4(l0, l1, l2, l3);
        }
    } else {                             // ---- B prep (hi only) ----
        int bb = b - c3;
        int layer = bb >= 320;
        int idx = (layer ? bb - 320 : bb) * 256 + tid;
        int n = idx & 127, k = idx >> 7;
        const float* basis = layer ? basis2 : basis1;
        const float* root  = layer ? root2  : root1;
        float v = (k < 512) ? basis[((k & 3) << 14) + ((k >> 2) << 7) + n]
                            : root[((k - 512) << 7) + n];
        size_t pos = (((size_t)(k >> 3) * 128) + n) * 8 + (k & 7);
        (layer ? Bp2h : Bp1h)[pos] = f2bf(v);
    }
}

// LDS slot permutation for Whi (r9-measured: conflicts 1.2M -> 0).
__device__ __forceinline__ int wslot(int n, int kh) {
    return (n + (kh >> 2) + ((kh & 3) << 3)) & 31;
}

// ---------------- FUSED layer: Xout = relu([agg(X)|X] @ B + bias) ----------------
// 512 threads, 32 nodes, 1 node per 16-lane gather group.
// VALU diet this round: float2 accumulators (v_pk_fma_f32 on gfx950) halve
// gather FMA issue; v_cvt_pk_bf16_f32 replaces 5-op f2bf in Whi/epilogue.
__global__ __launch_bounds__(512, 4) void layer_kernel(
    const unsigned short* __restrict__ Xh,    // [N,128] bf16 hi
    const unsigned short* __restrict__ Xl,    // [N,128] bf16 lo
    const int* __restrict__ row_start,
    const int4* __restrict__ rec,             // {src, et, norm, 0}
    const float* __restrict__ att,            // [R][4]
    const unsigned short* __restrict__ Bph,   // packed [80][128][8] bf16
    const float* __restrict__ bias,
    unsigned short* __restrict__ Xoh,
    unsigned short* __restrict__ Xol,
    int N)
{
    __shared__ unsigned short Whi[64 * 32 * 8];   // 32 KB (agg part only)

    const int tid   = threadIdx.x;
    const int node0 = blockIdx.x * 32;

    // ---- phase A: gather, 1 node per 16-lane group ----
    {
        const int g = tid >> 4, l = tid & 15;     // lane l covers dims 8l..8l+7
        const int gn = node0 + g;
        const bool ok = gn < N;
        int s0 = ok ? row_start[gn] : 0;
        int s1 = ok ? row_start[gn + 1] : 0;
        f2v acc2[4][4];                           // [dim-pair][basis]
        #pragma unroll
        for (int j = 0; j < 4; ++j)
            #pragma unroll
            for (int c = 0; c < 4; ++c) acc2[j][c] = (f2v){0.f, 0.f};

        const int se = s1 - 1;
        for (int q0 = s0; q0 < s1; q0 += 4) {
            int q1 = min(q0 + 1, se);
            int q2 = min(q0 + 2, se);
            int q3 = min(q0 + 3, se);
            int4 rA = rec[q0], rB = rec[q1], rC = rec[q2], rD = rec[q3];
            float4 tA = *(const float4*)&att[(size_t)rA.y * 4];
            float4 tB = *(const float4*)&att[(size_t)rB.y * 4];
            float4 tC = *(const float4*)&att[(size_t)rC.y * 4];
            float4 tD = *(const float4*)&att[(size_t)rD.y * 4];
            float nA = __int_as_float(rA.z), nB_ = __int_as_float(rB.z);
            float nC = __int_as_float(rC.z), nD = __int_as_float(rD.z);
            if (q0 + 1 > se) nB_ = 0.f;
            if (q0 + 2 > se) nC = 0.f;
            if (q0 + 3 > se) nD = 0.f;
            float cA[4] = {nA * tA.x, nA * tA.y, nA * tA.z, nA * tA.w};
            float cB[4] = {nB_ * tB.x, nB_ * tB.y, nB_ * tB.z, nB_ * tB.w};
            float cC[4] = {nC * tC.x, nC * tC.y, nC * tC.z, nC * tC.w};
            float cD[4] = {nD * tD.x, nD * tD.y, nD * tD.z, nD * tD.w};
            uint4 wA = *(const uint4*)&Xh[(size_t)rA.x * 128 + (l << 3)];
            uint4 wB = *(const uint4*)&Xh[(size_t)rB.x * 128 + (l << 3)];
            uint4 wC = *(const uint4*)&Xh[(size_t)rC.x * 128 + (l << 3)];
            uint4 wD = *(const uint4*)&Xh[(size_t)rD.x * 128 + (l << 3)];
            unsigned uA[4], uB[4], uC[4], uD[4];
            *(uint4*)uA = wA; *(uint4*)uB = wB; *(uint4*)uC = wC; *(uint4*)uD = wD;
            #pragma unroll
            for (int j = 0; j < 4; ++j) {
                f2v xA = {__uint_as_float(uA[j] << 16), __uint_as_float(uA[j] & 0xFFFF0000u)};
                f2v xB = {__uint_as_float(uB[j] << 16), __uint_as_float(uB[j] & 0xFFFF0000u)};
                f2v xC = {__uint_as_float(uC[j] << 16), __uint_as_float(uC[j] & 0xFFFF0000u)};
                f2v xD = {__uint_as_float(uD[j] << 16), __uint_as_float(uD[j] & 0xFFFF0000u)};
                #pragma unroll
                for (int c = 0; c < 4; ++c) {
                    f2v t = __builtin_elementwise_fma((f2v){cD[c], cD[c]}, xD, acc2[j][c]);
                    t     = __builtin_elementwise_fma((f2v){cC[c], cC[c]}, xC, t);
                    t     = __builtin_elementwise_fma((f2v){cB[c], cB[c]}, xB, t);
                    acc2[j][c] = __builtin_elementwise_fma((f2v){cA[c], cA[c]}, xA, t);
                }
            }
        }
        float inv = 1.0f / fmaxf((float)(s1 - s0), 1.0f);
        #pragma unroll
        for (int f = 0; f < 4; ++f) {             // fragment kh = 4l+f; dims {2f,2f+1}
            int kh   = 4 * l + f;
            int slot = wslot(g, kh);
            uint4 h;
            h.x = cvt2(acc2[f][0].x * inv, acc2[f][1].x * inv);
            h.y = cvt2(acc2[f][2].x * inv, acc2[f][3].x * inv);
            h.z = cvt2(acc2[f][0].y * inv, acc2[f][1].y * inv);
            h.w = cvt2(acc2[f][2].y * inv, acc2[f][3].y * inv);
            *(uint4*)&Whi[(kh * 32 + slot) * 8] = h;
        }
    }

    // ---- own-row X fragments direct from global (waves 0-3 only) ----
    const int lane = tid & 63, wv = tid >> 6;
    const int m    = lane & 31;
    const int kh8  = lane >> 5;
    s8v xh[8], xl[8];
    if (tid < 256) {
        const s8v z8 = {0, 0, 0, 0, 0, 0, 0, 0};
        int gn  = node0 + m;
        bool ok = gn < N;
        size_t xbase = (size_t)(ok ? gn : 0) * 128;
        #pragma unroll
        for (int q = 0; q < 8; ++q) {
            int dk = 2 * q + kh8;                 // == khg - 64
            xh[q] = *(const s8v*)&Xh[xbase + dk * 8];
            xl[q] = *(const s8v*)&Xl[xbase + dk * 8];
        }
        if (!ok) {
            #pragma unroll
            for (int q = 0; q < 8; ++q) { xh[q] = z8; xl[q] = z8; }
        }
    }
    __syncthreads();
    if (tid >= 256) return;                       // waves 4-7 done (no more barriers)

    // ---- phase B: barrier-free MFMA stream ----
    const int c0 = wv << 5;

    f16v acc;
    #pragma unroll
    for (int i = 0; i < 16; ++i) acc[i] = 0.f;

    s8v Bb[2][4];
    auto khg_of = [&](int t) {
        return (t < 8) ? (64 + 2 * t + kh8) : (2 * (t - 8) + kh8);
    };
    auto loadB4 = [&](int g, int buf) {
        #pragma unroll
        for (int q = 0; q < 4; ++q) {
            int khg = khg_of(g * 4 + q);
            size_t off = ((size_t)khg * 128 + c0 + m) * 8;
            Bb[buf][q] = *(const s8v*)&Bph[off];
        }
    };
    loadB4(0, 0);

    #pragma unroll
    for (int g = 0; g < 10; ++g) {
        int buf = g & 1;
        if (g < 9) loadB4(g + 1, buf ^ 1);
        #pragma unroll
        for (int q = 0; q < 4; ++q) {
            int t = g * 4 + q;
            if (t < 8) {
                acc = __builtin_amdgcn_mfma_f32_32x32x16_bf16(xl[t], Bb[buf][q], acc, 0, 0, 0);
                acc = __builtin_amdgcn_mfma_f32_32x32x16_bf16(xh[t], Bb[buf][q], acc, 0, 0, 0);
            } else {
                int khg  = 2 * (t - 8) + kh8;
                int slot = wslot(m, khg);
                s8v aH = *(const s8v*)&Whi[(khg * 32 + slot) * 8];
                acc = __builtin_amdgcn_mfma_f32_32x32x16_bf16(aH, Bb[buf][q], acc, 0, 0, 0);
            }
        }
    }

    // epilogue: 32x32 C/D: col = lane&31, row = (reg&3) + 8*(reg>>2) + 4*(lane>>5)
    // reg pairs (2k,2k+1) hit consecutive rows -> packed convert, split store.
    int gc = c0 + m;
    float bv = bias[gc];
    const int rbase = kh8 << 2;
    #pragma unroll
    for (int k = 0; k < 8; ++k) {
        int r0  = 2 * k;
        int gr0 = node0 + rbase + (r0 & 3) + ((r0 >> 2) << 3);
        float v0 = fmaxf(acc[r0] + bv, 0.f);
        float v1 = fmaxf(acc[r0 + 1] + bv, 0.f);
        unsigned hh = cvt2(v0, v1);
        unsigned ll = cvt2(v0 - __uint_as_float(hh << 16),
                           v1 - __uint_as_float(hh & 0xFFFF0000u));
        if (gr0 < N) {
            Xoh[(size_t)gr0 * 128 + gc] = (unsigned short)hh;
            Xol[(size_t)gr0 * 128 + gc] = (unsigned short)ll;
        }
        if (gr0 + 1 < N) {
            Xoh[(size_t)(gr0 + 1) * 128 + gc] = (unsigned short)(hh >> 16);
            Xol[(size_t)(gr0 + 1) * 128 + gc] = (unsigned short)(ll >> 16);
        }
    }
}

// ---------------- gated output: 8 samples per block ----------------
__global__ __launch_bounds__(256) void output_kernel(
    const int* __restrict__ samples,
    const float* __restrict__ gate_e,
    const float* __restrict__ gate_r,
    const float* __restrict__ ent_emb,
    const float* __restrict__ rel_emb,
    const unsigned short* __restrict__ ctx2h,
    const unsigned short* __restrict__ ctx2l,
    const float* __restrict__ relctx,
    float* __restrict__ out, int S)
{
    const int p   = blockIdx.y;
    const int o   = threadIdx.x & 127;
    const int sub = threadIdx.x >> 7;
    const float g = (p == 1) ? 1.0f / (1.0f + __expf(-gate_r[o]))
                             : 1.0f / (1.0f + __expf(-gate_e[o]));
    const int s0 = blockIdx.x * 8 + sub;
    #pragma unroll
    for (int k = 0; k < 4; ++k) {
        int s = s0 + k * 2;
        if (s >= S) break;
        float v;
        if (p == 1) {
            int idx = samples[s * 3 + 1];
            v = g * rel_emb[idx * 128 + o] + (1.0f - g) * relctx[idx * 128 + o];
        } else {
            int idx = samples[s * 3 + (p == 0 ? 0 : 2)];
            float c = bf2f(ctx2h[(size_t)idx * 128 + o]) + bf2f(ctx2l[(size_t)idx * 128 + o]);
            v = g * ent_emb[(size_t)idx * 128 + o] + (1.0f - g) * c;
        }
        out[(size_t)p * S * 128 + (size_t)s * 128 + o] = v;
    }
}

extern "C" void kernel_launch(void* const* d_in, const int* in_sizes, int n_in,
                              void* d_out, int out_size, void* d_ws, size_t ws_size,
                              hipStream_t stream)
{
    const int*   entity     = (const int*)d_in[0];
    const int*   edge_index = (const int*)d_in[1];
    const int*   edge_type  = (const int*)d_in[2];
    const float* edge_norm  = (const float*)d_in[3];
    const int*   samples    = (const int*)d_in[4];
    const float* DAD        = (const float*)d_in[5];
    const float* ent_emb    = (const float*)d_in[6];
    const float* rel_emb    = (const float*)d_in[7];
    const float* ent_tab    = (const float*)d_in[8];
    const float* rel_tab    = (const float*)d_in[9];
    const float* Wrel       = (const float*)d_in[10];
    const float* gate_e     = (const float*)d_in[11];
    const float* gate_r     = (const float*)d_in[12];
    const float* basis1     = (const float*)d_in[13];
    const float* att1       = (const float*)d_in[14];
    const float* root1      = (const float*)d_in[15];
    const float* bias1      = (const float*)d_in[16];
    const float* basis2     = (const float*)d_in[17];
    const float* att2       = (const float*)d_in[18];
    const float* root2      = (const float*)d_in[19];
    const float* bias2      = (const float*)d_in[20];

    const int N  = in_sizes[0];        // 50000
    const int E  = in_sizes[2];        // 200000
    const int S  = in_sizes[4] / 3;    // 20000
    const int NR = in_sizes[9] / 128;  // 200

    unsigned short* X0h = (unsigned short*)d_ws;       // [N,128] bf16
    unsigned short* X0l = X0h + (size_t)N * 128;
    unsigned short* X1h = X0l + (size_t)N * 128;       // layer1 out
    unsigned short* X1l = X1h + (size_t)N * 128;
    int4*  rec     = (int4*)(X1l + (size_t)N * 128);   // [E+4] {src,et,norm,0}
    float* Rc      = (float*)(rec + (E + 4));          // [NR,128]
    int*   deg     = (int*)(Rc + (size_t)NR * 128);    // [N]
    int*   rstart  = deg + N;                          // [N+1]
    int*   cursor  = rstart + N + 1;                   // [N]
    int*   btot    = cursor + N;                       // [64]
    uintptr_t bt   = ((uintptr_t)(btot + 64) + 15) & ~(uintptr_t)15;
    unsigned short* Bp1h = (unsigned short*)bt;        // [80*128*8]
    unsigned short* Bp2h = Bp1h + 80 * 128 * 8;

    const int egrid = (E + 255) / 256;
    const int lgrid = (N + 31) / 32;
    const int nB    = (N + 1023) / 1024;
    const int x0blocks = (N * 16 + 255) / 256;
    const int c1 = NR;
    const int c2 = c1 + egrid;
    const int c3 = c2 + x0blocks;
    const int mgrid = c3 + 640;

    hipMemsetAsync(deg, 0, (size_t)N * sizeof(int), stream);
    hist_kernel<<<egrid, 256, 0, stream>>>(edge_index, deg, E);
    scanA_kernel<<<nB, 1024, 0, stream>>>(deg, rstart, btot, N);
    scanC_kernel<<<nB, 1024, 0, stream>>>(rstart, cursor, btot, nB, N);
    mega_kernel<<<mgrid, 256, 0, stream>>>(
        DAD, rel_tab, Wrel, Rc, NR,
        edge_index, edge_type, edge_norm, cursor, rec, E,
        ent_tab, entity, X0h, X0l, N,
        basis1, root1, basis2, root2, Bp1h, Bp2h,
        c1, c2, c3);

    // ---- layer 1: X1 = relu([agg(X0)|X0] @ W1) ----
    layer_kernel<<<lgrid, 512, 0, stream>>>(X0h, X0l, rstart, rec, att1,
                                            Bp1h, bias1, X1h, X1l, N);
    // ---- layer 2: X0 = relu([agg(X1)|X1] @ W2)  (overwrites X0 buffers) ----
    layer_kernel<<<lgrid, 512, 0, stream>>>(X1h, X1l, rstart, rec, att2,
                                            Bp2h, bias2, X0h, X0l, N);

    // ---- gated output ----
    output_kernel<<<dim3((S + 7) / 8, 3), 256, 0, stream>>>(
        samples, gate_e, gate_r, ent_emb, rel_emb, X0h, X0l, Rc, (float*)d_out, S);
}